// Round 1
// baseline (858.520 us; speedup 1.0000x reference)
//
#include <hip/hip_runtime.h>
#include <hip/hip_bf16.h>
#include <math.h>

#define B_TOK 16384
#define DDIM  1024
#define NEXP  6
#define HDIM  256
#define EPSF  0.1f

typedef float f32x4 __attribute__((ext_vector_type(4)));
typedef short bf16x8 __attribute__((ext_vector_type(8)));

__device__ __forceinline__ unsigned short f2bf(float f) {
    unsigned int u = __float_as_uint(f);
    u += 0x7FFFu + ((u >> 16) & 1u);
    return (unsigned short)(u >> 16);
}

__device__ __forceinline__ float gelu_exact(float v) {
    return 0.5f * v * (1.0f + erff(v * 0.70710678118654752440f));
}

// ---------- transpose + convert: per-slice src (R x C) f32 -> dst (C x R) bf16
__global__ __launch_bounds__(256) void transpose_convert_kernel(
    const float* __restrict__ src, unsigned short* __restrict__ dst, int R, int C) {
    __shared__ float tile[32][33];
    const int e = blockIdx.z;
    const float* s = src + (size_t)e * R * C;
    unsigned short* d = dst + (size_t)e * R * C;
    const int cb = blockIdx.x * 32;
    const int rb = blockIdx.y * 32;
    const int tx = threadIdx.x;   // 0..31
    const int ty = threadIdx.y;   // 0..7
#pragma unroll
    for (int i = 0; i < 4; ++i)
        tile[ty + i * 8][tx] = s[(size_t)(rb + ty + i * 8) * C + cb + tx];
    __syncthreads();
#pragma unroll
    for (int i = 0; i < 4; ++i)
        d[(size_t)(cb + ty + i * 8) * R + rb + tx] = f2bf(tile[tx][ty + i * 8]);
}

// ---------- router: logits, softmax, eps-mix, top-2 scatter, load sums
__global__ __launch_bounds__(256) void router_kernel(
    const float* __restrict__ x, const float* __restrict__ Wr, const float* __restrict__ br,
    int* __restrict__ list, float* __restrict__ wlist,
    int* __restrict__ cnt, float* __restrict__ loadsum) {
    __shared__ float ls[NEXP];
    const int tid = threadIdx.x;
    if (tid < NEXP) ls[tid] = 0.0f;
    __syncthreads();

    const int wave = tid >> 6;
    const int lane = tid & 63;
    const int tok = blockIdx.x * 4 + wave;

    float acc[NEXP];
#pragma unroll
    for (int e = 0; e < NEXP; ++e) acc[e] = 0.0f;

    const float4* x4 = reinterpret_cast<const float4*>(x + (size_t)tok * DDIM);
#pragma unroll
    for (int it = 0; it < 4; ++it) {
        float4 xv = x4[it * 64 + lane];
        float xa[4] = {xv.x, xv.y, xv.z, xv.w};
        const int dbase = it * 256 + lane * 4;
        const float4* w4 = reinterpret_cast<const float4*>(Wr + (size_t)dbase * NEXP);
        float w[24];
#pragma unroll
        for (int q = 0; q < 6; ++q) *reinterpret_cast<float4*>(&w[q * 4]) = w4[q];
#pragma unroll
        for (int i2 = 0; i2 < 4; ++i2)
#pragma unroll
            for (int e = 0; e < NEXP; ++e)
                acc[e] += xa[i2] * w[i2 * NEXP + e];
    }
#pragma unroll
    for (int e = 0; e < NEXP; ++e) {
        float v = acc[e];
#pragma unroll
        for (int off = 32; off > 0; off >>= 1) v += __shfl_xor(v, off, 64);
        acc[e] = v;
    }

    // softmax + eps mix (all lanes redundantly; lane 0 commits)
    float p[NEXP];
    float m = -1e30f;
#pragma unroll
    for (int e = 0; e < NEXP; ++e) { p[e] = acc[e] + br[e]; m = fmaxf(m, p[e]); }
    float s = 0.0f;
#pragma unroll
    for (int e = 0; e < NEXP; ++e) { p[e] = expf(p[e] - m); s += p[e]; }
    const float inv = (1.0f - EPSF) / s;
#pragma unroll
    for (int e = 0; e < NEXP; ++e) p[e] = p[e] * inv + EPSF / (float)NEXP;

    if (lane == 0) {
        int b1i = 0; float bp = p[0];
#pragma unroll
        for (int e = 1; e < NEXP; ++e) if (p[e] > bp) { bp = p[e]; b1i = e; }
        int b2i = -1; float sp = -1e30f;
#pragma unroll
        for (int e = 0; e < NEXP; ++e) if (e != b1i && p[e] > sp) { sp = p[e]; b2i = e; }

        int s1 = atomicAdd(&cnt[b1i], 1);
        list[b1i * B_TOK + s1] = tok;  wlist[b1i * B_TOK + s1] = bp;
        int s2 = atomicAdd(&cnt[b2i], 1);
        list[b2i * B_TOK + s2] = tok;  wlist[b2i * B_TOK + s2] = sp;
#pragma unroll
        for (int e = 0; e < NEXP; ++e) atomicAdd(&ls[e], p[e]);
    }
    __syncthreads();
    if (tid < NEXP) atomicAdd(&loadsum[tid], ls[tid]);
}

// ---------- aux scalar
__global__ void aux_kernel(const float* __restrict__ loadsum, float* __restrict__ out) {
    if (threadIdx.x == 0) {
        float s = 0.0f;
#pragma unroll
        for (int e = 0; e < NEXP; ++e) {
            float ld = loadsum[e] / (float)B_TOK;
            s += ld * logf(ld * (float)NEXP + 1e-9f);
        }
        out[(size_t)B_TOK * DDIM] = s / logf((float)NEXP + 1e-9f);
    }
}

// ---------- fused expert MLP: per (expert, 64-token tile)
__global__ __launch_bounds__(256) void expert_kernel(
    const float* __restrict__ x,
    const unsigned short* __restrict__ w1t,   // (E, H, D) bf16 = W1^T per expert
    const unsigned short* __restrict__ w2t,   // (E, D, H) bf16 = W2^T per expert
    const float* __restrict__ b1,             // (E, H)
    const float* __restrict__ b2,             // (E, D)
    const int* __restrict__ list, const float* __restrict__ wlist,
    const int* __restrict__ cnt,
    float* __restrict__ out) {
    const int e = blockIdx.y;
    const int tile = blockIdx.x;
    const int n = cnt[e];
    if (tile * 64 >= n) return;

    __shared__ int   tok_l[64];
    __shared__ float wt_l[64];
    __shared__ __align__(16) char xs[64 * 64];     // 64 tok x 32 k bf16, xor-swizzled
    __shared__ __align__(16) char hsb[64 * 512];   // 64 tok x 256 hh bf16, xor-swizzled

    const int tid = threadIdx.x;
    const int lane = tid & 63;
    const int wave = tid >> 6;

    if (tid < 64) {
        int g = tile * 64 + tid;
        if (g < n) { tok_l[tid] = list[e * B_TOK + g]; wt_l[tid] = wlist[e * B_TOK + g]; }
        else       { tok_l[tid] = -1;                  wt_l[tid] = 0.0f; }
    }
    __syncthreads();

    // ---- stage 1: hT(256 x 64) = gelu(W1T (256x1024) . xT (1024x64) + b1)
    const int ti = tid >> 2;          // token slot this thread stages
    const int kc = (tid & 3) * 8;     // k-offset within 32-chunk
    const int tok_s = tok_l[ti];
    const float* xrow = x + (size_t)(tok_s < 0 ? 0 : tok_s) * DDIM + kc;
    int xs_woff = ti * 64 + kc * 2; xs_woff ^= (ti & 3) << 4;

    const unsigned short* w1e = w1t + (size_t)e * HDIM * DDIM;
    const int arow = wave * 64 + (lane & 15);
    const int kofs = (lane >> 4) * 8;

    f32x4 zero4 = {0.f, 0.f, 0.f, 0.f};
    f32x4 acc[4][4];
#pragma unroll
    for (int i = 0; i < 4; ++i)
#pragma unroll
        for (int j = 0; j < 4; ++j) acc[i][j] = zero4;

    for (int k0 = 0; k0 < DDIM; k0 += 32) {
        __syncthreads();   // prev-iter xs reads done
        float4 v0, v1;
        if (tok_s >= 0) {
            v0 = *reinterpret_cast<const float4*>(xrow + k0);
            v1 = *reinterpret_cast<const float4*>(xrow + k0 + 4);
        } else {
            v0 = make_float4(0.f, 0.f, 0.f, 0.f); v1 = v0;
        }
        int4 pk;
        pk.x = (int)f2bf(v0.x) | ((int)f2bf(v0.y) << 16);
        pk.y = (int)f2bf(v0.z) | ((int)f2bf(v0.w) << 16);
        pk.z = (int)f2bf(v1.x) | ((int)f2bf(v1.y) << 16);
        pk.w = (int)f2bf(v1.z) | ((int)f2bf(v1.w) << 16);
        *reinterpret_cast<int4*>(&xs[xs_woff]) = pk;
        __syncthreads();

        bf16x8 aF[4], bF[4];
#pragma unroll
        for (int mt = 0; mt < 4; ++mt)
            aF[mt] = *reinterpret_cast<const bf16x8*>(
                w1e + (size_t)(arow + mt * 16) * DDIM + k0 + kofs);
#pragma unroll
        for (int nt = 0; nt < 4; ++nt) {
            int t = nt * 16 + (lane & 15);
            int off = t * 64 + kofs * 2; off ^= (t & 3) << 4;
            bF[nt] = *reinterpret_cast<const bf16x8*>(&xs[off]);
        }
#pragma unroll
        for (int mt = 0; mt < 4; ++mt)
#pragma unroll
            for (int nt = 0; nt < 4; ++nt)
                acc[mt][nt] = __builtin_amdgcn_mfma_f32_16x16x32_bf16(
                    aF[mt], bF[nt], acc[mt][nt], 0, 0, 0);
    }

    // gelu + write hT fragments into hs (token-major, hh-contiguous packs of 4)
#pragma unroll
    for (int mt = 0; mt < 4; ++mt) {
        const int hh0 = wave * 64 + mt * 16 + (lane >> 4) * 4;
#pragma unroll
        for (int nt = 0; nt < 4; ++nt) {
            const int t = nt * 16 + (lane & 15);
            ushort4 hv;
            hv.x = f2bf(gelu_exact(acc[mt][nt][0] + b1[e * HDIM + hh0 + 0]));
            hv.y = f2bf(gelu_exact(acc[mt][nt][1] + b1[e * HDIM + hh0 + 1]));
            hv.z = f2bf(gelu_exact(acc[mt][nt][2] + b1[e * HDIM + hh0 + 2]));
            hv.w = f2bf(gelu_exact(acc[mt][nt][3] + b1[e * HDIM + hh0 + 3]));
            int off = t * 512 + hh0 * 2; off ^= (t & 7) << 4;
            *reinterpret_cast<ushort4*>(&hsb[off]) = hv;
        }
    }
    __syncthreads();

    // ---- stage 2: out(64 x 1024) += wt * (h (64x256) . W2 (256x1024) + b2)
    const unsigned short* w2e = w2t + (size_t)e * DDIM * HDIM;
#pragma unroll 1
    for (int c = 0; c < 4; ++c) {
        const int dbase = wave * 256 + c * 64;
        f32x4 a2[4][4];
#pragma unroll
        for (int i = 0; i < 4; ++i)
#pragma unroll
            for (int j = 0; j < 4; ++j) a2[i][j] = zero4;

        for (int hh0 = 0; hh0 < HDIM; hh0 += 32) {
            bf16x8 aF[4], bF[4];
#pragma unroll
            for (int mt = 0; mt < 4; ++mt) {
                int t = mt * 16 + (lane & 15);
                int off = t * 512 + (hh0 + kofs) * 2; off ^= (t & 7) << 4;
                aF[mt] = *reinterpret_cast<const bf16x8*>(&hsb[off]);
            }
#pragma unroll
            for (int nt = 0; nt < 4; ++nt)
                bF[nt] = *reinterpret_cast<const bf16x8*>(
                    w2e + (size_t)(dbase + nt * 16 + (lane & 15)) * HDIM + hh0 + kofs);
#pragma unroll
            for (int mt = 0; mt < 4; ++mt)
#pragma unroll
                for (int nt = 0; nt < 4; ++nt)
                    a2[mt][nt] = __builtin_amdgcn_mfma_f32_16x16x32_bf16(
                        aF[mt], bF[nt], a2[mt][nt], 0, 0, 0);
        }

        // epilogue: weighted atomic accumulate
#pragma unroll
        for (int mt = 0; mt < 4; ++mt) {
            const int t0 = mt * 16 + (lane >> 4) * 4;
            int   tkj[4]; float wtj[4];
#pragma unroll
            for (int j = 0; j < 4; ++j) { tkj[j] = tok_l[t0 + j]; wtj[j] = wt_l[t0 + j]; }
#pragma unroll
            for (int nt = 0; nt < 4; ++nt) {
                const int d = dbase + nt * 16 + (lane & 15);
                const float bias = b2[e * DDIM + d];
#pragma unroll
                for (int j = 0; j < 4; ++j) {
                    if (tkj[j] >= 0)
                        atomicAdd(out + (size_t)tkj[j] * DDIM + d,
                                  wtj[j] * (a2[mt][nt][j] + bias));
                }
            }
        }
    }
}

extern "C" void kernel_launch(void* const* d_in, const int* in_sizes, int n_in,
                              void* d_out, int out_size, void* d_ws, size_t ws_size,
                              hipStream_t stream) {
    const float* x  = (const float*)d_in[0];
    const float* Wr = (const float*)d_in[1];
    const float* br = (const float*)d_in[2];
    const float* W1 = (const float*)d_in[3];
    const float* b1 = (const float*)d_in[4];
    const float* W2 = (const float*)d_in[5];
    const float* b2 = (const float*)d_in[6];
    float* out = (float*)d_out;

    char* ws = (char*)d_ws;
    unsigned short* w1t   = (unsigned short*)(ws + 0);         // E*H*D*2 = 3,145,728 B
    unsigned short* w2t   = (unsigned short*)(ws + 3145728);   // 3,145,728 B
    int*            list  = (int*)(ws + 6291456);              // E*B*4   =   393,216 B
    float*          wlist = (float*)(ws + 6684672);            //             393,216 B
    int*            cnt   = (int*)(ws + 7077888);              // 6 ints
    float*          lsum  = (float*)(ws + 7077888 + 256);      // 6 floats

    hipMemsetAsync(cnt, 0, 512, stream);                               // cnt + lsum
    hipMemsetAsync(d_out, 0, (size_t)out_size * sizeof(float), stream);

    // W1 (E, D=1024, H=256) -> w1t (E, H, D);  W2 (E, H=256, D=1024) -> w2t (E, D, H)
    transpose_convert_kernel<<<dim3(HDIM / 32, DDIM / 32, NEXP), dim3(32, 8), 0, stream>>>(
        W1, w1t, DDIM, HDIM);
    transpose_convert_kernel<<<dim3(DDIM / 32, HDIM / 32, NEXP), dim3(32, 8), 0, stream>>>(
        W2, w2t, HDIM, DDIM);

    router_kernel<<<dim3(B_TOK / 4), dim3(256), 0, stream>>>(x, Wr, br, list, wlist, cnt, lsum);
    aux_kernel<<<1, 64, 0, stream>>>(lsum, out);
    expert_kernel<<<dim3(B_TOK / 64, NEXP), dim3(256), 0, stream>>>(
        x, w1t, w2t, b1, b2, list, wlist, cnt, out);
}

// Round 2
// 496.101 us; speedup vs baseline: 1.7305x; 1.7305x over previous
//
#include <hip/hip_runtime.h>
#include <hip/hip_bf16.h>
#include <math.h>

#define B_TOK 16384
#define DDIM  1024
#define NEXP  6
#define HDIM  256
#define EPSF  0.1f

typedef float f32x4 __attribute__((ext_vector_type(4)));
typedef short bf16x8 __attribute__((ext_vector_type(8)));

__device__ __forceinline__ unsigned short f2bf(float f) {
    unsigned int u = __float_as_uint(f);
    u += 0x7FFFu + ((u >> 16) & 1u);
    return (unsigned short)(u >> 16);
}

__device__ __forceinline__ int pack2bf(float a, float b) {
    return (int)f2bf(a) | ((int)f2bf(b) << 16);
}

__device__ __forceinline__ float gelu_exact(float v) {
    return 0.5f * v * (1.0f + erff(v * 0.70710678118654752440f));
}

// ---------- transpose + convert: per-slice src (R x C) f32 -> dst (C x R) bf16
__global__ __launch_bounds__(256) void transpose_convert_kernel(
    const float* __restrict__ src, unsigned short* __restrict__ dst, int R, int C) {
    __shared__ float tile[32][33];
    const int e = blockIdx.z;
    const float* s = src + (size_t)e * R * C;
    unsigned short* d = dst + (size_t)e * R * C;
    const int cb = blockIdx.x * 32;
    const int rb = blockIdx.y * 32;
    const int tx = threadIdx.x;   // 0..31
    const int ty = threadIdx.y;   // 0..7
#pragma unroll
    for (int i = 0; i < 4; ++i)
        tile[ty + i * 8][tx] = s[(size_t)(rb + ty + i * 8) * C + cb + tx];
    __syncthreads();
#pragma unroll
    for (int i = 0; i < 4; ++i)
        d[(size_t)(cb + ty + i * 8) * R + rb + tx] = f2bf(tile[tx][ty + i * 8]);
}

// ---------- router phase 1: logits, softmax, eps-mix, top-2 -> per-token records
// No global atomics: per-block load partial sums via plain stores.
__global__ __launch_bounds__(256) void router1_kernel(
    const float* __restrict__ x, const float* __restrict__ Wr, const float* __restrict__ br,
    int* __restrict__ erec, float2* __restrict__ wrec, float* __restrict__ partial) {
    __shared__ float ls[NEXP];
    const int tid = threadIdx.x;
    if (tid < NEXP) ls[tid] = 0.0f;
    __syncthreads();

    const int wave = tid >> 6;
    const int lane = tid & 63;

    float lsacc[NEXP];
#pragma unroll
    for (int e = 0; e < NEXP; ++e) lsacc[e] = 0.0f;

#pragma unroll 1
    for (int j = 0; j < 4; ++j) {
        const int tok = blockIdx.x * 16 + wave * 4 + j;

        float acc[NEXP];
#pragma unroll
        for (int e = 0; e < NEXP; ++e) acc[e] = 0.0f;

        const float4* x4 = reinterpret_cast<const float4*>(x + (size_t)tok * DDIM);
#pragma unroll
        for (int it = 0; it < 4; ++it) {
            float4 xv = x4[it * 64 + lane];
            float xa[4] = {xv.x, xv.y, xv.z, xv.w};
            const int dbase = it * 256 + lane * 4;
            const float4* w4 = reinterpret_cast<const float4*>(Wr + (size_t)dbase * NEXP);
            float w[24];
#pragma unroll
            for (int q = 0; q < 6; ++q) *reinterpret_cast<float4*>(&w[q * 4]) = w4[q];
#pragma unroll
            for (int i2 = 0; i2 < 4; ++i2)
#pragma unroll
                for (int e = 0; e < NEXP; ++e)
                    acc[e] += xa[i2] * w[i2 * NEXP + e];
        }
#pragma unroll
        for (int e = 0; e < NEXP; ++e) {
            float v = acc[e];
#pragma unroll
            for (int off = 32; off > 0; off >>= 1) v += __shfl_xor(v, off, 64);
            acc[e] = v;
        }

        // softmax + eps mix (all lanes redundantly, wave-uniform)
        float p[NEXP];
        float m = -1e30f;
#pragma unroll
        for (int e = 0; e < NEXP; ++e) { p[e] = acc[e] + br[e]; m = fmaxf(m, p[e]); }
        float s = 0.0f;
#pragma unroll
        for (int e = 0; e < NEXP; ++e) { p[e] = expf(p[e] - m); s += p[e]; }
        const float inv = (1.0f - EPSF) / s;
#pragma unroll
        for (int e = 0; e < NEXP; ++e) p[e] = p[e] * inv + EPSF / (float)NEXP;

        // top-2, strict-greater => lowest index on ties (matches lax.top_k)
        int b1i = 0; float bp = p[0];
#pragma unroll
        for (int e = 1; e < NEXP; ++e) if (p[e] > bp) { bp = p[e]; b1i = e; }
        int b2i = -1; float sp = -1e30f;
#pragma unroll
        for (int e = 0; e < NEXP; ++e) if (e != b1i && p[e] > sp) { sp = p[e]; b2i = e; }

        if (lane == 0) {
            erec[tok] = b1i | (b2i << 16);
            wrec[tok] = make_float2(bp, sp);
        }
#pragma unroll
        for (int e = 0; e < NEXP; ++e) lsacc[e] += p[e];
    }

    if (lane == 0) {
#pragma unroll
        for (int e = 0; e < NEXP; ++e) atomicAdd(&ls[e], lsacc[e]);
    }
    __syncthreads();
    if (tid < NEXP) partial[blockIdx.x * NEXP + tid] = ls[tid];
}

// ---------- router phase 2: build per-expert token lists (LDS atomics + 6 global/block)
__global__ __launch_bounds__(1024) void router2_kernel(
    const int* __restrict__ erec, const float2* __restrict__ wrec,
    int* __restrict__ list, float* __restrict__ wlist, int* __restrict__ cnt) {
    __shared__ int lc[NEXP];
    __shared__ int gb[NEXP];
    const int tid = threadIdx.x;
    if (tid < NEXP) lc[tid] = 0;
    __syncthreads();

    const int tok = blockIdx.x * 1024 + tid;
    const int er = erec[tok];
    const float2 wr = wrec[tok];
    const int e1 = er & 0xffff;
    const int e2 = er >> 16;
    const int i1 = atomicAdd(&lc[e1], 1);
    const int i2 = atomicAdd(&lc[e2], 1);
    __syncthreads();
    if (tid < NEXP) gb[tid] = atomicAdd(&cnt[tid], lc[tid]);
    __syncthreads();

    const int p1 = gb[e1] + i1;
    list[e1 * B_TOK + p1] = tok;  wlist[e1 * B_TOK + p1] = wr.x;
    const int p2 = gb[e2] + i2;
    list[e2 * B_TOK + p2] = tok;  wlist[e2 * B_TOK + p2] = wr.y;
}

// ---------- aux scalar: reduce per-block load partials
__global__ void aux_kernel(const float* __restrict__ partial, float* __restrict__ out) {
    const int lane = threadIdx.x;   // 64 threads
    float s[NEXP];
#pragma unroll
    for (int e = 0; e < NEXP; ++e) s[e] = 0.0f;
    for (int i = lane; i < 1024; i += 64) {
#pragma unroll
        for (int e = 0; e < NEXP; ++e) s[e] += partial[i * NEXP + e];
    }
#pragma unroll
    for (int e = 0; e < NEXP; ++e) {
        float v = s[e];
#pragma unroll
        for (int off = 32; off > 0; off >>= 1) v += __shfl_xor(v, off, 64);
        s[e] = v;
    }
    if (lane == 0) {
        float a = 0.0f;
#pragma unroll
        for (int e = 0; e < NEXP; ++e) {
            float ld = s[e] / (float)B_TOK;
            a += ld * logf(ld * (float)NEXP + 1e-9f);
        }
        out[(size_t)B_TOK * DDIM] = a / logf((float)NEXP + 1e-9f);
    }
}

// ---------- fused expert MLP: per (expert, 64-token tile)
// Stage 1: BK=64 double-buffered LDS, async-split staging (issue loads -> MFMA -> write).
// Stage 2: h (LDS, aliased over x-staging) x W2^T (global), weighted atomic epilogue.
__global__ __launch_bounds__(256) void expert_kernel(
    const float* __restrict__ x,
    const unsigned short* __restrict__ w1t,   // (E, H, D) bf16 = W1^T per expert
    const unsigned short* __restrict__ w2t,   // (E, D, H) bf16 = W2^T per expert
    const float* __restrict__ b1,             // (E, H)
    const float* __restrict__ b2,             // (E, D)
    const int* __restrict__ list, const float* __restrict__ wlist,
    const int* __restrict__ cnt,
    float* __restrict__ out) {
    const int e = blockIdx.y;
    const int tile = blockIdx.x;
    const int n = cnt[e];
    if (tile * 64 >= n) return;

    __shared__ int   tok_l[64];
    __shared__ float wt_l[64];
    // xs double buffer: 2 x (64 tok x 64 k bf16) = 2 x 8KB.  hsb (64 tok x 256 h bf16,
    // 32KB) ALIASES the same region -- written only after the final stage-1 barrier.
    __shared__ __align__(16) char smem[32768];

    const int tid = threadIdx.x;
    const int lane = tid & 63;
    const int wave = tid >> 6;

    if (tid < 64) {
        int g = tile * 64 + tid;
        if (g < n) { tok_l[tid] = list[e * B_TOK + g]; wt_l[tid] = wlist[e * B_TOK + g]; }
        else       { tok_l[tid] = -1;                  wt_l[tid] = 0.0f; }
    }
    __syncthreads();

    // staging role: thread covers 16 consecutive fp32 of one token row per chunk
    const int ti = tid >> 2;          // token slot
    const int q  = tid & 3;           // quarter (16 floats = 2 bf16 16B-chunks)
    const int tok_s = tok_l[ti];
    const float* xrow = x + (size_t)(tok_s < 0 ? 0 : tok_s) * DDIM;
    // swizzled LDS write offsets (row = 128B = 8 16B-chunks; XOR chunkidx with ti&7)
    const int woff0 = ti * 128 + (((q * 2    ) ^ (ti & 7)) << 4);
    const int woff1 = ti * 128 + (((q * 2 + 1) ^ (ti & 7)) << 4);

    const unsigned short* w1e = w1t + (size_t)e * HDIM * DDIM;
    const int arow = wave * 64 + (lane & 15);
    const int kofs = (lane >> 4) * 8;

    f32x4 zero4 = {0.f, 0.f, 0.f, 0.f};
    f32x4 acc[4][4];
#pragma unroll
    for (int i = 0; i < 4; ++i)
#pragma unroll
        for (int j = 0; j < 4; ++j) acc[i][j] = zero4;

    float4 pf0, pf1, pf2, pf3;
    // prologue: stage chunk 0
    {
        const float4* p = reinterpret_cast<const float4*>(xrow + q * 16);
        pf0 = p[0]; pf1 = p[1]; pf2 = p[2]; pf3 = p[3];
        int4 wa, wb;
        wa.x = pack2bf(pf0.x, pf0.y); wa.y = pack2bf(pf0.z, pf0.w);
        wa.z = pack2bf(pf1.x, pf1.y); wa.w = pack2bf(pf1.z, pf1.w);
        wb.x = pack2bf(pf2.x, pf2.y); wb.y = pack2bf(pf2.z, pf2.w);
        wb.z = pack2bf(pf3.x, pf3.y); wb.w = pack2bf(pf3.z, pf3.w);
        if (tok_s < 0) { wa = make_int4(0,0,0,0); wb = wa; }
        *reinterpret_cast<int4*>(smem + woff0) = wa;
        *reinterpret_cast<int4*>(smem + woff1) = wb;
    }
    __syncthreads();

#pragma unroll 1
    for (int c = 0; c < 16; ++c) {
        char* cur = smem + ((c & 1) << 13);
        char* nxt = smem + (((c + 1) & 1) << 13);
        // T14: issue next chunk's global loads BEFORE this chunk's MFMAs
        if (c < 15) {
            const float4* p = reinterpret_cast<const float4*>(xrow + (c + 1) * 64 + q * 16);
            pf0 = p[0]; pf1 = p[1]; pf2 = p[2]; pf3 = p[3];
        }
        // compute chunk c: 2 k-steps x 16 MFMA
#pragma unroll
        for (int ks = 0; ks < 2; ++ks) {
            const int kk = c * 64 + ks * 32 + kofs;
            bf16x8 aF[4], bF[4];
#pragma unroll
            for (int mt = 0; mt < 4; ++mt)
                aF[mt] = *reinterpret_cast<const bf16x8*>(
                    w1e + (size_t)(arow + mt * 16) * DDIM + kk);
#pragma unroll
            for (int nt = 0; nt < 4; ++nt) {
                const int t = nt * 16 + (lane & 15);
                const int ch = ks * 4 + (lane >> 4);
                bF[nt] = *reinterpret_cast<const bf16x8*>(
                    cur + t * 128 + ((ch ^ (t & 7)) << 4));
            }
#pragma unroll
            for (int mt = 0; mt < 4; ++mt)
#pragma unroll
                for (int nt = 0; nt < 4; ++nt)
                    acc[mt][nt] = __builtin_amdgcn_mfma_f32_16x16x32_bf16(
                        aF[mt], bF[nt], acc[mt][nt], 0, 0, 0);
        }
        __syncthreads();   // all reads of both buffers done
        if (c < 15) {
            int4 wa, wb;
            wa.x = pack2bf(pf0.x, pf0.y); wa.y = pack2bf(pf0.z, pf0.w);
            wa.z = pack2bf(pf1.x, pf1.y); wa.w = pack2bf(pf1.z, pf1.w);
            wb.x = pack2bf(pf2.x, pf2.y); wb.y = pack2bf(pf2.z, pf2.w);
            wb.z = pack2bf(pf3.x, pf3.y); wb.w = pack2bf(pf3.z, pf3.w);
            if (tok_s < 0) { wa = make_int4(0,0,0,0); wb = wa; }
            *reinterpret_cast<int4*>(nxt + woff0) = wa;
            *reinterpret_cast<int4*>(nxt + woff1) = wb;
            __syncthreads();
        }
    }

    // gelu + write hT into hsb (aliases smem; safe after final barrier above)
#pragma unroll
    for (int mt = 0; mt < 4; ++mt) {
        const int hh0 = wave * 64 + mt * 16 + (lane >> 4) * 4;
#pragma unroll
        for (int nt = 0; nt < 4; ++nt) {
            const int t = nt * 16 + (lane & 15);
            ushort4 hv;
            hv.x = f2bf(gelu_exact(acc[mt][nt][0] + b1[e * HDIM + hh0 + 0]));
            hv.y = f2bf(gelu_exact(acc[mt][nt][1] + b1[e * HDIM + hh0 + 1]));
            hv.z = f2bf(gelu_exact(acc[mt][nt][2] + b1[e * HDIM + hh0 + 2]));
            hv.w = f2bf(gelu_exact(acc[mt][nt][3] + b1[e * HDIM + hh0 + 3]));
            int off = t * 512 + hh0 * 2; off ^= (t & 7) << 4;
            *reinterpret_cast<ushort4*>(smem + off) = hv;
        }
    }
    __syncthreads();

    // ---- stage 2: out(64 x 1024) += wt * (h (64x256) . W2 (256x1024) + b2)
    const unsigned short* w2e = w2t + (size_t)e * DDIM * HDIM;
#pragma unroll 1
    for (int c = 0; c < 4; ++c) {
        const int dbase = wave * 256 + c * 64;
        f32x4 a2[4][4];
#pragma unroll
        for (int i = 0; i < 4; ++i)
#pragma unroll
            for (int j = 0; j < 4; ++j) a2[i][j] = zero4;

        for (int hh0 = 0; hh0 < HDIM; hh0 += 32) {
            bf16x8 aF[4], bF[4];
#pragma unroll
            for (int mt = 0; mt < 4; ++mt) {
                const int t = mt * 16 + (lane & 15);
                int off = t * 512 + (hh0 + kofs) * 2; off ^= (t & 7) << 4;
                aF[mt] = *reinterpret_cast<const bf16x8*>(smem + off);
            }
#pragma unroll
            for (int nt = 0; nt < 4; ++nt)
                bF[nt] = *reinterpret_cast<const bf16x8*>(
                    w2e + (size_t)(dbase + nt * 16 + (lane & 15)) * HDIM + hh0 + kofs);
#pragma unroll
            for (int mt = 0; mt < 4; ++mt)
#pragma unroll
                for (int nt = 0; nt < 4; ++nt)
                    a2[mt][nt] = __builtin_amdgcn_mfma_f32_16x16x32_bf16(
                        aF[mt], bF[nt], a2[mt][nt], 0, 0, 0);
        }

        // epilogue: weighted atomic accumulate
#pragma unroll
        for (int mt = 0; mt < 4; ++mt) {
            const int t0 = mt * 16 + (lane >> 4) * 4;
            int   tkj[4]; float wtj[4];
#pragma unroll
            for (int j = 0; j < 4; ++j) { tkj[j] = tok_l[t0 + j]; wtj[j] = wt_l[t0 + j]; }
#pragma unroll
            for (int nt = 0; nt < 4; ++nt) {
                const int d = dbase + nt * 16 + (lane & 15);
                const float bias = b2[e * DDIM + d];
#pragma unroll
                for (int j = 0; j < 4; ++j) {
                    if (tkj[j] >= 0)
                        atomicAdd(out + (size_t)tkj[j] * DDIM + d,
                                  wtj[j] * (a2[mt][nt][j] + bias));
                }
            }
        }
    }
}

extern "C" void kernel_launch(void* const* d_in, const int* in_sizes, int n_in,
                              void* d_out, int out_size, void* d_ws, size_t ws_size,
                              hipStream_t stream) {
    const float* x  = (const float*)d_in[0];
    const float* Wr = (const float*)d_in[1];
    const float* br = (const float*)d_in[2];
    const float* W1 = (const float*)d_in[3];
    const float* b1 = (const float*)d_in[4];
    const float* W2 = (const float*)d_in[5];
    const float* b2 = (const float*)d_in[6];
    float* out = (float*)d_out;

    char* ws = (char*)d_ws;
    unsigned short* w1t   = (unsigned short*)(ws + 0);          // 3,145,728 B
    unsigned short* w2t   = (unsigned short*)(ws + 3145728);    // 3,145,728 B
    int*            list  = (int*)(ws + 6291456);               //   393,216 B
    float*          wlist = (float*)(ws + 6684672);             //   393,216 B
    int*            erec  = (int*)(ws + 7077888);               //    65,536 B
    float2*         wrec  = (float2*)(ws + 7143424);            //   131,072 B
    float*          partial = (float*)(ws + 7274496);           //    24,576 B
    int*            cnt   = (int*)(ws + 7299072);               //        64 B

    hipMemsetAsync(cnt, 0, 64, stream);
    hipMemsetAsync(d_out, 0, (size_t)out_size * sizeof(float), stream);

    // W1 (E, D=1024, H=256) -> w1t (E, H, D);  W2 (E, H=256, D=1024) -> w2t (E, D, H)
    transpose_convert_kernel<<<dim3(HDIM / 32, DDIM / 32, NEXP), dim3(32, 8), 0, stream>>>(
        W1, w1t, DDIM, HDIM);
    transpose_convert_kernel<<<dim3(DDIM / 32, HDIM / 32, NEXP), dim3(32, 8), 0, stream>>>(
        W2, w2t, HDIM, DDIM);

    router1_kernel<<<dim3(B_TOK / 16), dim3(256), 0, stream>>>(x, Wr, br, erec, wrec, partial);
    router2_kernel<<<dim3(B_TOK / 1024), dim3(1024), 0, stream>>>(erec, wrec, list, wlist, cnt);
    aux_kernel<<<1, 64, 0, stream>>>(partial, out);
    expert_kernel<<<dim3(B_TOK / 64, NEXP), dim3(256), 0, stream>>>(
        x, w1t, w2t, b1, b2, list, wlist, cnt, out);
}

// Round 3
// 432.223 us; speedup vs baseline: 1.9863x; 1.1478x over previous
//
#include <hip/hip_runtime.h>
#include <hip/hip_bf16.h>
#include <math.h>

#define B_TOK 16384
#define DDIM  1024
#define NEXP  6
#define NPAIR 15
#define HDIM  256
#define EPSF  0.1f
#define TILE  32
#define MAXTILES (B_TOK / TILE + NPAIR)   // 527

typedef float f32x4 __attribute__((ext_vector_type(4)));
typedef short bf16x8 __attribute__((ext_vector_type(8)));

__device__ __forceinline__ unsigned short f2bf(float f) {
    unsigned int u = __float_as_uint(f);
    u += 0x7FFFu + ((u >> 16) & 1u);
    return (unsigned short)(u >> 16);
}
__device__ __forceinline__ int pack2bf(float a, float b) {
    return (int)f2bf(a) | ((int)f2bf(b) << 16);
}
__device__ __forceinline__ float gelu_exact(float v) {
    return 0.5f * v * (1.0f + erff(v * 0.70710678118654752440f));
}

// ---------- transpose + convert: per-slice src (R x C) f32 -> dst (C x R) bf16
__global__ __launch_bounds__(256) void transpose_convert_kernel(
    const float* __restrict__ src, unsigned short* __restrict__ dst, int R, int C) {
    __shared__ float tile[32][33];
    const int e = blockIdx.z;
    const float* s = src + (size_t)e * R * C;
    unsigned short* d = dst + (size_t)e * R * C;
    const int cb = blockIdx.x * 32;
    const int rb = blockIdx.y * 32;
    const int tx = threadIdx.x;
    const int ty = threadIdx.y;
#pragma unroll
    for (int i = 0; i < 4; ++i)
        tile[ty + i * 8][tx] = s[(size_t)(rb + ty + i * 8) * C + cb + tx];
    __syncthreads();
#pragma unroll
    for (int i = 0; i < 4; ++i)
        d[(size_t)(cb + ty + i * 8) * R + rb + tx] = f2bf(tile[tx][ty + i * 8]);
}

// ---------- router phase 1: logits, softmax, eps-mix, top-2 -> per-token records
__global__ __launch_bounds__(256) void router1_kernel(
    const float* __restrict__ x, const float* __restrict__ Wr, const float* __restrict__ br,
    int* __restrict__ erec, float2* __restrict__ wrec, float* __restrict__ partial) {
    __shared__ float ls[NEXP];
    const int tid = threadIdx.x;
    if (tid < NEXP) ls[tid] = 0.0f;
    __syncthreads();

    const int wave = tid >> 6;
    const int lane = tid & 63;
    const int tok0 = blockIdx.x * 16 + wave * 4;

    float acc[4][NEXP];
#pragma unroll
    for (int j = 0; j < 4; ++j)
#pragma unroll
        for (int e = 0; e < NEXP; ++e) acc[j][e] = 0.0f;

#pragma unroll
    for (int it = 0; it < 4; ++it) {
        // hoisted Wr slice for this lane's 4 dims (invariant across the 4 tokens)
        const float4* w4 = reinterpret_cast<const float4*>(
            Wr + (size_t)(it * 256 + lane * 4) * NEXP);
        float w[24];
#pragma unroll
        for (int q = 0; q < 6; ++q) *reinterpret_cast<float4*>(&w[q * 4]) = w4[q];
#pragma unroll
        for (int j = 0; j < 4; ++j) {
            float4 xv = reinterpret_cast<const float4*>(
                x + (size_t)(tok0 + j) * DDIM)[it * 64 + lane];
            float xa[4] = {xv.x, xv.y, xv.z, xv.w};
#pragma unroll
            for (int i2 = 0; i2 < 4; ++i2)
#pragma unroll
                for (int e = 0; e < NEXP; ++e)
                    acc[j][e] += xa[i2] * w[i2 * NEXP + e];
        }
    }

    float lsacc[NEXP];
#pragma unroll
    for (int e = 0; e < NEXP; ++e) lsacc[e] = 0.0f;

#pragma unroll
    for (int j = 0; j < 4; ++j) {
        float p[NEXP];
        float m = -1e30f;
#pragma unroll
        for (int e = 0; e < NEXP; ++e) {
            float v = acc[j][e];
#pragma unroll
            for (int off = 32; off > 0; off >>= 1) v += __shfl_xor(v, off, 64);
            p[e] = v + br[e];
            m = fmaxf(m, p[e]);
        }
        float s = 0.0f;
#pragma unroll
        for (int e = 0; e < NEXP; ++e) { p[e] = expf(p[e] - m); s += p[e]; }
        const float inv = (1.0f - EPSF) / s;
#pragma unroll
        for (int e = 0; e < NEXP; ++e) p[e] = p[e] * inv + EPSF / (float)NEXP;

        int b1i = 0; float bp = p[0];
#pragma unroll
        for (int e = 1; e < NEXP; ++e) if (p[e] > bp) { bp = p[e]; b1i = e; }
        int b2i = -1; float sp = -1e30f;
#pragma unroll
        for (int e = 0; e < NEXP; ++e) if (e != b1i && p[e] > sp) { sp = p[e]; b2i = e; }

        if (lane == 0) {
            erec[tok0 + j] = b1i | (b2i << 16);
            wrec[tok0 + j] = make_float2(bp, sp);
        }
#pragma unroll
        for (int e = 0; e < NEXP; ++e) lsacc[e] += p[e];
    }

    if (lane == 0) {
#pragma unroll
        for (int e = 0; e < NEXP; ++e) atomicAdd(&ls[e], lsacc[e]);
    }
    __syncthreads();
    if (tid < NEXP) partial[blockIdx.x * NEXP + tid] = ls[tid];
}

// ---------- router phase 2: bucket tokens by unordered expert pair
__global__ __launch_bounds__(1024) void router2_kernel(
    const int* __restrict__ erec, const float2* __restrict__ wrec,
    int* __restrict__ plist, float2* __restrict__ wpair, int* __restrict__ cnt) {
    __shared__ int lc[NPAIR];
    __shared__ int gb[NPAIR];
    const int tid = threadIdx.x;
    if (tid < NPAIR) lc[tid] = 0;
    __syncthreads();

    const int tok = blockIdx.x * 1024 + tid;
    const int er = erec[tok];
    const float2 wr = wrec[tok];
    const int e1 = er & 0xffff;
    const int e2 = er >> 16;
    const int a = min(e1, e2);
    const int b = max(e1, e2);
    const float wa = (a == e1) ? wr.x : wr.y;
    const float wb = (a == e1) ? wr.y : wr.x;
    const int p = a * (11 - a) / 2 + (b - a - 1);

    const int i = atomicAdd(&lc[p], 1);
    __syncthreads();
    if (tid < NPAIR) gb[tid] = atomicAdd(&cnt[tid], lc[tid]);
    __syncthreads();

    const int pos = gb[p] + i;
    plist[p * B_TOK + pos] = tok;
    wpair[p * B_TOK + pos] = make_float2(wa, wb);
}

// ---------- router phase 3: tile -> (pair, local tile) mapping table
__global__ void router3_kernel(const int* __restrict__ cnt, int* __restrict__ table) {
    if (threadIdx.x == 0) {
        int off = 0;
        for (int p = 0; p < NPAIR; ++p) {
            const int t = (cnt[p] + TILE - 1) / TILE;
            for (int i = 0; i < t; ++i) table[1 + off + i] = (p << 16) | i;
            off += t;
        }
        table[0] = off;
    }
}

// ---------- aux scalar
__global__ void aux_kernel(const float* __restrict__ partial, float* __restrict__ out) {
    const int lane = threadIdx.x;   // 64
    float s[NEXP];
#pragma unroll
    for (int e = 0; e < NEXP; ++e) s[e] = 0.0f;
    for (int i = lane; i < 1024; i += 64) {
#pragma unroll
        for (int e = 0; e < NEXP; ++e) s[e] += partial[i * NEXP + e];
    }
#pragma unroll
    for (int e = 0; e < NEXP; ++e) {
        float v = s[e];
#pragma unroll
        for (int off = 32; off > 0; off >>= 1) v += __shfl_xor(v, off, 64);
        s[e] = v;
    }
    if (lane == 0) {
        float a = 0.0f;
#pragma unroll
        for (int e = 0; e < NEXP; ++e) {
            float ld = s[e] / (float)B_TOK;
            a += ld * logf(ld * (float)NEXP + 1e-9f);
        }
        out[(size_t)B_TOK * DDIM] = a / logf((float)NEXP + 1e-9f);
    }
}

// ---------- pair-fused expert MLP: 32-token tile of one expert pair, atomic-free
__global__ __launch_bounds__(256) void expert_kernel(
    const float* __restrict__ x,
    const unsigned short* __restrict__ w1t,   // (E, H, D) bf16
    const unsigned short* __restrict__ w2t,   // (E, D, H) bf16
    const float* __restrict__ b1,             // (E, H)
    const float* __restrict__ b2,             // (E, D)
    const int* __restrict__ plist, const float2* __restrict__ wpair,
    const int* __restrict__ cnt, const int* __restrict__ table,
    float* __restrict__ out) {
    const int g = blockIdx.x;
    if (g >= table[0]) return;
    const int code = table[1 + g];
    const int p = code >> 16;
    const int lt = code & 0xffff;
    const int n = cnt[p];

    // invert triangular pair index
    int a, b;
    if      (p < 5)  { a = 0; b = p + 1; }
    else if (p < 9)  { a = 1; b = p - 3; }
    else if (p < 12) { a = 2; b = p - 6; }
    else if (p < 14) { a = 3; b = p - 8; }
    else             { a = 4; b = 5; }

    __shared__ int   tok_l[TILE];
    __shared__ float wa_l[TILE];
    __shared__ float wb_l[TILE];
    // hA: [0,16384) ; hB: [16384,32768). x dbuf (2 x 4KB) aliases hA[0,8192).
    __shared__ __align__(16) char smem[32768];

    const int tid = threadIdx.x;
    const int lane = tid & 63;
    const int wave = tid >> 6;

    if (tid < TILE) {
        const int gi = lt * TILE + tid;
        if (gi < n) {
            tok_l[tid] = plist[p * B_TOK + gi];
            float2 w2 = wpair[p * B_TOK + gi];
            wa_l[tid] = w2.x; wb_l[tid] = w2.y;
        } else { tok_l[tid] = -1; wa_l[tid] = 0.0f; wb_l[tid] = 0.0f; }
    }
    __syncthreads();

    // ---- stage 1: hX^T(256 x 32) = wX * gelu(W1X^T . x^T + b1X), X = A (waves 0-1), B (waves 2-3)
    const int ti = tid >> 3;          // token slot 0..31
    const int q  = tid & 7;           // 16B chunk within 128B row
    const int tok_s = tok_l[ti];
    const float* xrow = x + (size_t)(tok_s < 0 ? 0 : tok_s) * DDIM;
    const int woff = ti * 128 + ((q ^ (ti & 7)) << 4);

    const int wexp = (wave < 2) ? a : b;
    const unsigned short* w1e = w1t + (size_t)wexp * HDIM * DDIM;
    const int hrow0 = (wave & 1) * 128;
    const int arow = hrow0 + (lane & 15);
    const int kofs = (lane >> 4) * 8;

    f32x4 zero4 = {0.f, 0.f, 0.f, 0.f};
    f32x4 acc[8][2];
#pragma unroll
    for (int i = 0; i < 8; ++i) { acc[i][0] = zero4; acc[i][1] = zero4; }

    float4 pf0, pf1;
    {
        const float4* ps = reinterpret_cast<const float4*>(xrow + q * 8);
        pf0 = ps[0]; pf1 = ps[1];
        int4 wv;
        wv.x = pack2bf(pf0.x, pf0.y); wv.y = pack2bf(pf0.z, pf0.w);
        wv.z = pack2bf(pf1.x, pf1.y); wv.w = pack2bf(pf1.z, pf1.w);
        if (tok_s < 0) wv = make_int4(0, 0, 0, 0);
        *reinterpret_cast<int4*>(smem + woff) = wv;
    }
    __syncthreads();

#pragma unroll 1
    for (int c = 0; c < 16; ++c) {
        char* cur = smem + ((c & 1) << 12);
        char* nxt = smem + (((c + 1) & 1) << 12);
        if (c < 15) {
            const float4* ps = reinterpret_cast<const float4*>(xrow + (c + 1) * 64 + q * 8);
            pf0 = ps[0]; pf1 = ps[1];
        }
#pragma unroll
        for (int ks = 0; ks < 2; ++ks) {
            const int kk = c * 64 + ks * 32 + kofs;
            bf16x8 aF[8], bF[2];
#pragma unroll
            for (int nt = 0; nt < 2; ++nt) {
                const int t = nt * 16 + (lane & 15);
                const int ch = ks * 4 + (lane >> 4);
                bF[nt] = *reinterpret_cast<const bf16x8*>(
                    cur + t * 128 + ((ch ^ (t & 7)) << 4));
            }
#pragma unroll
            for (int mt = 0; mt < 8; ++mt)
                aF[mt] = *reinterpret_cast<const bf16x8*>(
                    w1e + (size_t)(arow + mt * 16) * DDIM + kk);
#pragma unroll
            for (int mt = 0; mt < 8; ++mt)
#pragma unroll
                for (int nt = 0; nt < 2; ++nt)
                    acc[mt][nt] = __builtin_amdgcn_mfma_f32_16x16x32_bf16(
                        aF[mt], bF[nt], acc[mt][nt], 0, 0, 0);
        }
        __syncthreads();
        if (c < 15) {
            int4 wv;
            wv.x = pack2bf(pf0.x, pf0.y); wv.y = pack2bf(pf0.z, pf0.w);
            wv.z = pack2bf(pf1.x, pf1.y); wv.w = pack2bf(pf1.z, pf1.w);
            if (tok_s < 0) wv = make_int4(0, 0, 0, 0);
            *reinterpret_cast<int4*>(nxt + woff) = wv;
            __syncthreads();
        }
    }

    // gelu + gate-weight scale + write h^T (bf16) into hA / hB
    char* hdst = smem + ((wave < 2) ? 0 : 16384);
#pragma unroll
    for (int mt = 0; mt < 8; ++mt) {
        const int hh0 = hrow0 + mt * 16 + (lane >> 4) * 4;
        const float4 bb = *reinterpret_cast<const float4*>(b1 + wexp * HDIM + hh0);
#pragma unroll
        for (int nt = 0; nt < 2; ++nt) {
            const int t = nt * 16 + (lane & 15);
            const float wt = (wave < 2) ? wa_l[t] : wb_l[t];
            ushort4 hv;
            hv.x = f2bf(wt * gelu_exact(acc[mt][nt][0] + bb.x));
            hv.y = f2bf(wt * gelu_exact(acc[mt][nt][1] + bb.y));
            hv.z = f2bf(wt * gelu_exact(acc[mt][nt][2] + bb.z));
            hv.w = f2bf(wt * gelu_exact(acc[mt][nt][3] + bb.w));
            int off = t * 512 + hh0 * 2; off ^= (t & 7) << 4;
            *reinterpret_cast<ushort4*>(hdst + off) = hv;
        }
    }
    __syncthreads();

    // ---- stage 2: out(32 x 1024) = hA . W2A + hB . W2B + (wa*b2A + wb*b2B)
    const unsigned short* w2a = w2t + (size_t)a * DDIM * HDIM;
    const unsigned short* w2b = w2t + (size_t)b * DDIM * HDIM;
#pragma unroll 1
    for (int c = 0; c < 4; ++c) {
        const int dbase = wave * 256 + c * 64;
        f32x4 a2[2][4];
#pragma unroll
        for (int i = 0; i < 2; ++i)
#pragma unroll
            for (int j = 0; j < 4; ++j) a2[i][j] = zero4;

#pragma unroll
        for (int hh0 = 0; hh0 < HDIM; hh0 += 32) {
            bf16x8 aF[2], bF[4];
#pragma unroll
            for (int mt = 0; mt < 2; ++mt) {
                const int t = mt * 16 + (lane & 15);
                int off = t * 512 + (hh0 + kofs) * 2; off ^= (t & 7) << 4;
                aF[mt] = *reinterpret_cast<const bf16x8*>(smem + off);
            }
#pragma unroll
            for (int nt = 0; nt < 4; ++nt)
                bF[nt] = *reinterpret_cast<const bf16x8*>(
                    w2a + (size_t)(dbase + nt * 16 + (lane & 15)) * HDIM + hh0 + kofs);
#pragma unroll
            for (int mt = 0; mt < 2; ++mt)
#pragma unroll
                for (int nt = 0; nt < 4; ++nt)
                    a2[mt][nt] = __builtin_amdgcn_mfma_f32_16x16x32_bf16(
                        aF[mt], bF[nt], a2[mt][nt], 0, 0, 0);
        }
#pragma unroll
        for (int hh0 = 0; hh0 < HDIM; hh0 += 32) {
            bf16x8 aF[2], bF[4];
#pragma unroll
            for (int mt = 0; mt < 2; ++mt) {
                const int t = mt * 16 + (lane & 15);
                int off = t * 512 + (hh0 + kofs) * 2; off ^= (t & 7) << 4;
                aF[mt] = *reinterpret_cast<const bf16x8*>(smem + 16384 + off);
            }
#pragma unroll
            for (int nt = 0; nt < 4; ++nt)
                bF[nt] = *reinterpret_cast<const bf16x8*>(
                    w2b + (size_t)(dbase + nt * 16 + (lane & 15)) * HDIM + hh0 + kofs);
#pragma unroll
            for (int mt = 0; mt < 2; ++mt)
#pragma unroll
                for (int nt = 0; nt < 4; ++nt)
                    a2[mt][nt] = __builtin_amdgcn_mfma_f32_16x16x32_bf16(
                        aF[mt], bF[nt], a2[mt][nt], 0, 0, 0);
        }

        // epilogue: single plain store per output element
#pragma unroll
        for (int mt = 0; mt < 2; ++mt) {
            const int t0 = mt * 16 + (lane >> 4) * 4;
            int tkj[4]; float waj[4], wbj[4];
#pragma unroll
            for (int j = 0; j < 4; ++j) {
                tkj[j] = tok_l[t0 + j]; waj[j] = wa_l[t0 + j]; wbj[j] = wb_l[t0 + j];
            }
#pragma unroll
            for (int nt = 0; nt < 4; ++nt) {
                const int d = dbase + nt * 16 + (lane & 15);
                const float bA = b2[a * DDIM + d];
                const float bB = b2[b * DDIM + d];
#pragma unroll
                for (int j = 0; j < 4; ++j) {
                    if (tkj[j] >= 0)
                        out[(size_t)tkj[j] * DDIM + d] =
                            a2[mt][nt][j] + waj[j] * bA + wbj[j] * bB;
                }
            }
        }
    }
}

extern "C" void kernel_launch(void* const* d_in, const int* in_sizes, int n_in,
                              void* d_out, int out_size, void* d_ws, size_t ws_size,
                              hipStream_t stream) {
    const float* x  = (const float*)d_in[0];
    const float* Wr = (const float*)d_in[1];
    const float* br = (const float*)d_in[2];
    const float* W1 = (const float*)d_in[3];
    const float* b1 = (const float*)d_in[4];
    const float* W2 = (const float*)d_in[5];
    const float* b2 = (const float*)d_in[6];
    float* out = (float*)d_out;

    char* ws = (char*)d_ws;
    unsigned short* w1t   = (unsigned short*)(ws + 0);          // 3,145,728
    unsigned short* w2t   = (unsigned short*)(ws + 3145728);    // 3,145,728
    int*            plist = (int*)(ws + 6291456);               //   983,040
    float2*         wpair = (float2*)(ws + 7274496);            // 1,966,080
    int*            erec  = (int*)(ws + 9240576);               //    65,536
    float2*         wrec  = (float2*)(ws + 9306112);            //   131,072
    float*          partial = (float*)(ws + 9437184);           //    24,576
    int*            cnt   = (int*)(ws + 9461760);               //       256
    int*            table = (int*)(ws + 9462016);               //     2,560

    hipMemsetAsync(cnt, 0, 256, stream);

    transpose_convert_kernel<<<dim3(HDIM / 32, DDIM / 32, NEXP), dim3(32, 8), 0, stream>>>(
        W1, w1t, DDIM, HDIM);
    transpose_convert_kernel<<<dim3(DDIM / 32, HDIM / 32, NEXP), dim3(32, 8), 0, stream>>>(
        W2, w2t, HDIM, DDIM);

    router1_kernel<<<dim3(B_TOK / 16), dim3(256), 0, stream>>>(x, Wr, br, erec, wrec, partial);
    router2_kernel<<<dim3(B_TOK / 1024), dim3(1024), 0, stream>>>(erec, wrec, plist, wpair, cnt);
    router3_kernel<<<1, 64, 0, stream>>>(cnt, table);
    aux_kernel<<<1, 64, 0, stream>>>(partial, out);
    expert_kernel<<<dim3(MAXTILES), dim3(256), 0, stream>>>(
        x, w1t, w2t, b1, b2, plist, wpair, cnt, table, out);
}